// Round 2
// baseline (2362.017 us; speedup 1.0000x reference)
//
#include <hip/hip_runtime.h>

#define N_NODES 100000
#define N_EDGES 600000
#define D 128
#define TM 64     // rows (edges or nodes) per block tile
#define KB 16     // K step

// ws layout (floats): [Wt_intra: D*D][Wt_inter: D*D][intra_src: N_NODES*D]
// Wt[k*D+d] = W[d*D+k] so GEMM staging reads are coalesced.

__global__ void transpose_w_kernel(const float* __restrict__ Wi,
                                   const float* __restrict__ We,
                                   float* __restrict__ Wti,
                                   float* __restrict__ Wte) {
    int i = blockIdx.x * blockDim.x + threadIdx.x;
    if (i < D * D) {
        int d = i / D, k = i % D;
        Wti[k * D + d] = Wi[i];
        Wte[k * D + d] = We[i];
    }
}

// Tiled GEMM: rows = concat(src_x, dst_x) (2N rows), C = X @ W_intra^T.
// Rows [0,N) -> intra_src, rows [N,2N) -> out (pre-activation self_msg).
// Block: 256 threads, tile 64 rows x 128 cols, K-step 16, 4x8 acc/thread.
__global__ __launch_bounds__(256) void node_gemm_kernel(
    const float* __restrict__ src_x, const float* __restrict__ dst_x,
    const float* __restrict__ Wt, float* __restrict__ intra,
    float* __restrict__ out) {
    __shared__ float pT[D][TM];    // [k][m] 32 KB, full K panel of X^T
    __shared__ float wT[KB][D];    // [k][n] 8 KB

    int t = threadIdx.x;
    int r0 = blockIdx.x * TM;

    // stage X^T panel (transpose during load; coalesced float4 global reads)
    {
        int m = t & 63;
        int kq = t >> 6;                    // 0..3
        int r = r0 + m;
        const float* xr = (r < N_NODES) ? src_x + (size_t)r * D
                                        : dst_x + (size_t)(r - N_NODES) * D;
        #pragma unroll
        for (int i = 0; i < 8; ++i) {
            int k0 = kq * 32 + i * 4;
            float4 a = *(const float4*)(xr + k0);
            pT[k0 + 0][m] = a.x;
            pT[k0 + 1][m] = a.y;
            pT[k0 + 2][m] = a.z;
            pT[k0 + 3][m] = a.w;
        }
    }

    int tm = t & 15;    // row group: rows tm*4..+3
    int tn = t >> 4;    // col group: cols tn*8..+7
    float acc[4][8];
    #pragma unroll
    for (int i = 0; i < 4; ++i)
        #pragma unroll
        for (int j = 0; j < 8; ++j) acc[i][j] = 0.f;

    for (int kb = 0; kb < D; kb += KB) {
        __syncthreads();
        #pragma unroll
        for (int p = 0; p < 2; ++p) {
            int flat = p * 1024 + t * 4;
            *(float4*)((float*)wT + flat) =
                *(const float4*)(Wt + (size_t)kb * D + flat);
        }
        __syncthreads();
        #pragma unroll
        for (int k = 0; k < KB; ++k) {
            float4 pv = *(const float4*)&pT[kb + k][tm * 4];
            float4 wa = *(const float4*)&wT[k][tn * 8];
            float4 wb = *(const float4*)&wT[k][tn * 8 + 4];
            float pm[4] = {pv.x, pv.y, pv.z, pv.w};
            float wv[8] = {wa.x, wa.y, wa.z, wa.w, wb.x, wb.y, wb.z, wb.w};
            #pragma unroll
            for (int i = 0; i < 4; ++i)
                #pragma unroll
                for (int j = 0; j < 8; ++j)
                    acc[i][j] += pm[i] * wv[j];
        }
    }

    int n0 = tn * 8;
    #pragma unroll
    for (int i = 0; i < 4; ++i) {
        int r = r0 + tm * 4 + i;
        float* orow = (r < N_NODES) ? intra + (size_t)r * D
                                    : out + (size_t)(r - N_NODES) * D;
        float4 va = {acc[i][0], acc[i][1], acc[i][2], acc[i][3]};
        float4 vb = {acc[i][4], acc[i][5], acc[i][6], acc[i][7]};
        *(float4*)(orow + n0) = va;
        *(float4*)(orow + n0 + 4) = vb;
    }
}

// Tiled GEMM over edges: P[e,k] = src_x[s_e][k]*dst_x[t_e][k], M = P @ W_inter^T,
// msg = ew_e * (intra_src[s_e] + M), atomicAdd into out[t_e].
__global__ __launch_bounds__(256) void edge_gemm_kernel(
    const float* __restrict__ src_x, const float* __restrict__ dst_x,
    const int* __restrict__ src_idx, const int* __restrict__ dst_idx,
    const float* __restrict__ ew, const float* __restrict__ Wt,
    const float* __restrict__ intra, float* __restrict__ out) {
    __shared__ float pT[D][TM];    // [k][m] 32 KB, full K panel of P^T
    __shared__ float wT[KB][D];    // [k][n] 8 KB
    __shared__ int sI[TM];
    __shared__ int tI[TM];
    __shared__ float eW[TM];

    int t = threadIdx.x;
    int e0 = blockIdx.x * TM;

    if (t < TM) {
        sI[t] = src_idx[e0 + t];
        tI[t] = dst_idx[e0 + t];
        eW[t] = ew[e0 + t];
    }
    __syncthreads();

    // stage P^T panel (gathered float4 reads from random node rows)
    {
        int m = t & 63;
        int kq = t >> 6;
        const float* sr = src_x + (size_t)sI[m] * D;
        const float* dr = dst_x + (size_t)tI[m] * D;
        #pragma unroll
        for (int i = 0; i < 8; ++i) {
            int k0 = kq * 32 + i * 4;
            float4 a = *(const float4*)(sr + k0);
            float4 b = *(const float4*)(dr + k0);
            pT[k0 + 0][m] = a.x * b.x;
            pT[k0 + 1][m] = a.y * b.y;
            pT[k0 + 2][m] = a.z * b.z;
            pT[k0 + 3][m] = a.w * b.w;
        }
    }

    int tm = t & 15;
    int tn = t >> 4;
    float acc[4][8];
    #pragma unroll
    for (int i = 0; i < 4; ++i)
        #pragma unroll
        for (int j = 0; j < 8; ++j) acc[i][j] = 0.f;

    for (int kb = 0; kb < D; kb += KB) {
        __syncthreads();
        #pragma unroll
        for (int p = 0; p < 2; ++p) {
            int flat = p * 1024 + t * 4;
            *(float4*)((float*)wT + flat) =
                *(const float4*)(Wt + (size_t)kb * D + flat);
        }
        __syncthreads();
        #pragma unroll
        for (int k = 0; k < KB; ++k) {
            float4 pv = *(const float4*)&pT[kb + k][tm * 4];
            float4 wa = *(const float4*)&wT[k][tn * 8];
            float4 wb = *(const float4*)&wT[k][tn * 8 + 4];
            float pm[4] = {pv.x, pv.y, pv.z, pv.w};
            float wv[8] = {wa.x, wa.y, wa.z, wa.w, wb.x, wb.y, wb.z, wb.w};
            #pragma unroll
            for (int i = 0; i < 4; ++i)
                #pragma unroll
                for (int j = 0; j < 8; ++j)
                    acc[i][j] += pm[i] * wv[j];
        }
    }

    // epilogue: msg = ew*(intra[s] + acc); atomic scatter into out[t]
    int n0 = tn * 8;
    #pragma unroll
    for (int i = 0; i < 4; ++i) {
        int m = tm * 4 + i;
        int s = sI[m];
        float w = eW[m];
        const float* ir = intra + (size_t)s * D + n0;
        float4 ia = *(const float4*)(ir);
        float4 ib = *(const float4*)(ir + 4);
        float vals[8] = {ia.x, ia.y, ia.z, ia.w, ib.x, ib.y, ib.z, ib.w};
        float* orow = out + (size_t)tI[m] * D + n0;
        #pragma unroll
        for (int j = 0; j < 8; ++j)
            atomicAdd(orow + j, w * (vals[j] + acc[i][j]));
    }
}

__global__ void leaky_relu_kernel(float* __restrict__ out, int n) {
    int i = blockIdx.x * blockDim.x + threadIdx.x;
    if (i < n) {
        float v = out[i];
        out[i] = v > 0.0f ? v : 0.01f * v;
    }
}

extern "C" void kernel_launch(void* const* d_in, const int* in_sizes, int n_in,
                              void* d_out, int out_size, void* d_ws, size_t ws_size,
                              hipStream_t stream) {
    const float* src_x = (const float*)d_in[0];
    const float* dst_x = (const float*)d_in[1];
    const int*   eidx  = (const int*)d_in[2];     // [2, E] flat: src then dst
    const float* ew    = (const float*)d_in[3];   // [E, 1]
    const float* Wi    = (const float*)d_in[4];   // [D, D]
    const float* We    = (const float*)d_in[5];   // [D, D]
    float* out = (float*)d_out;

    float* ws    = (float*)d_ws;
    float* Wti   = ws;                 // D*D
    float* Wte   = ws + D * D;         // D*D
    float* intra = ws + 2 * D * D;     // N_NODES*D

    const int* src_idx = eidx;
    const int* dst_idx = eidx + N_EDGES;

    transpose_w_kernel<<<(D * D + 255) / 256, 256, 0, stream>>>(Wi, We, Wti, Wte);

    node_gemm_kernel<<<(2 * N_NODES) / TM, 256, 0, stream>>>(src_x, dst_x, Wti,
                                                             intra, out);

    edge_gemm_kernel<<<N_EDGES / TM, 256, 0, stream>>>(src_x, dst_x, src_idx,
                                                       dst_idx, ew, Wte, intra, out);

    leaky_relu_kernel<<<(N_NODES * D + 255) / 256, 256, 0, stream>>>(out, N_NODES * D);
}

// Round 3
// 740.469 us; speedup vs baseline: 3.1899x; 3.1899x over previous
//
#include <hip/hip_runtime.h>

#define N_NODES 100000
#define N_EDGES 600000
#define D 128
#define TM 64     // rows (edges or nodes) per block tile
#define KB 16     // K step
#define CT_STRIDE 129   // padded row stride for C-tile LDS round-trip

// ws layout (floats): [Wt_intra: D*D][Wt_inter: D*D][intra_src: N_NODES*D]
// Wt[k*D+d] = W[d*D+k] so GEMM staging reads are coalesced.

__global__ void transpose_w_kernel(const float* __restrict__ Wi,
                                   const float* __restrict__ We,
                                   float* __restrict__ Wti,
                                   float* __restrict__ Wte) {
    int i = blockIdx.x * blockDim.x + threadIdx.x;
    if (i < D * D) {
        int d = i / D, k = i % D;
        Wti[k * D + d] = Wi[i];
        Wte[k * D + d] = We[i];
    }
}

// Tiled GEMM: rows = concat(src_x, dst_x) (2N rows), C = X @ W_intra^T.
// Rows [0,N) -> intra_src, rows [N,2N) -> out (pre-activation self_msg).
__global__ __launch_bounds__(256) void node_gemm_kernel(
    const float* __restrict__ src_x, const float* __restrict__ dst_x,
    const float* __restrict__ Wt, float* __restrict__ intra,
    float* __restrict__ out) {
    __shared__ float pT[D][TM];    // [k][m] 32 KB, full K panel of X^T
    __shared__ float wT[KB][D];    // [k][n] 8 KB

    int t = threadIdx.x;
    int r0 = blockIdx.x * TM;

    {
        int m = t & 63;
        int kq = t >> 6;                    // 0..3
        int r = r0 + m;
        const float* xr = (r < N_NODES) ? src_x + (size_t)r * D
                                        : dst_x + (size_t)(r - N_NODES) * D;
        #pragma unroll
        for (int i = 0; i < 8; ++i) {
            int k0 = kq * 32 + i * 4;
            float4 a = *(const float4*)(xr + k0);
            pT[k0 + 0][m] = a.x;
            pT[k0 + 1][m] = a.y;
            pT[k0 + 2][m] = a.z;
            pT[k0 + 3][m] = a.w;
        }
    }

    int tm = t & 15;    // row group: rows tm*4..+3
    int tn = t >> 4;    // col group: cols tn*8..+7
    float acc[4][8];
    #pragma unroll
    for (int i = 0; i < 4; ++i)
        #pragma unroll
        for (int j = 0; j < 8; ++j) acc[i][j] = 0.f;

    for (int kb = 0; kb < D; kb += KB) {
        __syncthreads();
        #pragma unroll
        for (int p = 0; p < 2; ++p) {
            int flat = p * 1024 + t * 4;
            *(float4*)((float*)wT + flat) =
                *(const float4*)(Wt + (size_t)kb * D + flat);
        }
        __syncthreads();
        #pragma unroll
        for (int k = 0; k < KB; ++k) {
            float4 pv = *(const float4*)&pT[kb + k][tm * 4];
            float4 wa = *(const float4*)&wT[k][tn * 8];
            float4 wb = *(const float4*)&wT[k][tn * 8 + 4];
            float pm[4] = {pv.x, pv.y, pv.z, pv.w};
            float wv[8] = {wa.x, wa.y, wa.z, wa.w, wb.x, wb.y, wb.z, wb.w};
            #pragma unroll
            for (int i = 0; i < 4; ++i)
                #pragma unroll
                for (int j = 0; j < 8; ++j)
                    acc[i][j] += pm[i] * wv[j];
        }
    }

    int n0 = tn * 8;
    #pragma unroll
    for (int i = 0; i < 4; ++i) {
        int r = r0 + tm * 4 + i;
        float* orow = (r < N_NODES) ? intra + (size_t)r * D
                                    : out + (size_t)(r - N_NODES) * D;
        float4 va = {acc[i][0], acc[i][1], acc[i][2], acc[i][3]};
        float4 vb = {acc[i][4], acc[i][5], acc[i][6], acc[i][7]};
        *(float4*)(orow + n0) = va;
        *(float4*)(orow + n0 + 4) = vb;
    }
}

// Tiled GEMM over edges: P[e,k] = src_x[s_e][k]*dst_x[t_e][k], M = P @ W_inter^T,
// msg = ew_e * (intra_src[s_e] + M), atomicAdd into out[t_e].
// Epilogue round-trips C tile through LDS so atomics are lane-consecutive
// within each destination row (coalesced -> line-merged at L2).
__global__ __launch_bounds__(256) void edge_gemm_kernel(
    const float* __restrict__ src_x, const float* __restrict__ dst_x,
    const int* __restrict__ src_idx, const int* __restrict__ dst_idx,
    const float* __restrict__ ew, const float* __restrict__ Wt,
    const float* __restrict__ intra, float* __restrict__ out) {
    // sbuf doubles as pT[k][m] (8192 floats) during GEMM, then C[m][c]
    // (64 x stride-129 = 8256 floats) during the epilogue.
    __shared__ float sbuf[TM * CT_STRIDE];
    __shared__ float wT[KB][D];
    __shared__ int sI[TM];
    __shared__ int tI[TM];
    __shared__ float eW[TM];
#define PT(k, m) sbuf[(k) * TM + (m)]
#define CT(m, c) sbuf[(m) * CT_STRIDE + (c)]

    int t = threadIdx.x;
    int e0 = blockIdx.x * TM;

    if (t < TM) {
        sI[t] = src_idx[e0 + t];
        tI[t] = dst_idx[e0 + t];
        eW[t] = ew[e0 + t];
    }
    __syncthreads();

    // stage P^T panel (gathered float4 reads from random node rows)
    {
        int m = t & 63;
        int kq = t >> 6;
        const float* sr = src_x + (size_t)sI[m] * D;
        const float* dr = dst_x + (size_t)tI[m] * D;
        #pragma unroll
        for (int i = 0; i < 8; ++i) {
            int k0 = kq * 32 + i * 4;
            float4 a = *(const float4*)(sr + k0);
            float4 b = *(const float4*)(dr + k0);
            PT(k0 + 0, m) = a.x * b.x;
            PT(k0 + 1, m) = a.y * b.y;
            PT(k0 + 2, m) = a.z * b.z;
            PT(k0 + 3, m) = a.w * b.w;
        }
    }

    int tm = t & 15;
    int tn = t >> 4;
    float acc[4][8];
    #pragma unroll
    for (int i = 0; i < 4; ++i)
        #pragma unroll
        for (int j = 0; j < 8; ++j) acc[i][j] = 0.f;

    for (int kb = 0; kb < D; kb += KB) {
        __syncthreads();
        #pragma unroll
        for (int p = 0; p < 2; ++p) {
            int flat = p * 1024 + t * 4;
            *(float4*)((float*)wT + flat) =
                *(const float4*)(Wt + (size_t)kb * D + flat);
        }
        __syncthreads();
        #pragma unroll
        for (int k = 0; k < KB; ++k) {
            float4 pv = *(const float4*)&PT(kb + k, tm * 4);
            float4 wa = *(const float4*)&wT[k][tn * 8];
            float4 wb = *(const float4*)&wT[k][tn * 8 + 4];
            float pm[4] = {pv.x, pv.y, pv.z, pv.w};
            float wv[8] = {wa.x, wa.y, wa.z, wa.w, wb.x, wb.y, wb.z, wb.w};
            #pragma unroll
            for (int i = 0; i < 4; ++i)
                #pragma unroll
                for (int j = 0; j < 8; ++j)
                    acc[i][j] += pm[i] * wv[j];
        }
    }

    // --- epilogue: acc -> LDS C tile (pT is dead) -> coalesced atomic scatter
    __syncthreads();   // all waves done reading pT
    int n0 = tn * 8;
    #pragma unroll
    for (int i = 0; i < 4; ++i)
        #pragma unroll
        for (int j = 0; j < 8; ++j)
            CT(tm * 4 + i, n0 + j) = acc[i][j];
    __syncthreads();

    int c = t & 127;          // column
    int half = t >> 7;        // 0/1: two rows in flight
    for (int it = 0; it < TM / 2; ++it) {
        int m = it * 2 + half;
        int s = sI[m];        // wave-uniform -> scalar load
        float msg = eW[m] * (intra[(size_t)s * D + c] + CT(m, c));
        atomicAdd(out + (size_t)tI[m] * D + c, msg);
    }
#undef PT
#undef CT
}

__global__ void leaky_relu_kernel(float* __restrict__ out, int n) {
    int i = blockIdx.x * blockDim.x + threadIdx.x;
    if (i < n) {
        float v = out[i];
        out[i] = v > 0.0f ? v : 0.01f * v;
    }
}

extern "C" void kernel_launch(void* const* d_in, const int* in_sizes, int n_in,
                              void* d_out, int out_size, void* d_ws, size_t ws_size,
                              hipStream_t stream) {
    const float* src_x = (const float*)d_in[0];
    const float* dst_x = (const float*)d_in[1];
    const int*   eidx  = (const int*)d_in[2];     // [2, E] flat: src then dst
    const float* ew    = (const float*)d_in[3];   // [E, 1]
    const float* Wi    = (const float*)d_in[4];   // [D, D]
    const float* We    = (const float*)d_in[5];   // [D, D]
    float* out = (float*)d_out;

    float* ws    = (float*)d_ws;
    float* Wti   = ws;                 // D*D
    float* Wte   = ws + D * D;         // D*D
    float* intra = ws + 2 * D * D;     // N_NODES*D

    const int* src_idx = eidx;
    const int* dst_idx = eidx + N_EDGES;

    transpose_w_kernel<<<(D * D + 255) / 256, 256, 0, stream>>>(Wi, We, Wti, Wte);

    node_gemm_kernel<<<(2 * N_NODES) / TM, 256, 0, stream>>>(src_x, dst_x, Wti,
                                                             intra, out);

    edge_gemm_kernel<<<N_EDGES / TM, 256, 0, stream>>>(src_x, dst_x, src_idx,
                                                       dst_idx, ew, Wte, intra, out);

    leaky_relu_kernel<<<(N_NODES * D + 255) / 256, 256, 0, stream>>>(out, N_NODES * D);
}

// Round 4
// 500.489 us; speedup vs baseline: 4.7194x; 1.4795x over previous
//
#include <hip/hip_runtime.h>

#define N_NODES 100000
#define N_EDGES 600000
#define D 128

typedef __attribute__((ext_vector_type(8))) short short8;
typedef __attribute__((ext_vector_type(8))) unsigned short ushort8;
typedef __attribute__((ext_vector_type(4))) float f32x4;

__device__ __forceinline__ float bf2f(unsigned short u) {
    return __uint_as_float(((unsigned)u) << 16);
}
__device__ __forceinline__ unsigned short f2bf(float f) {
    unsigned u = __float_as_uint(f);
    u += 0x7FFF + ((u >> 16) & 1);   // RNE
    return (unsigned short)(u >> 16);
}

// ws layout (ushorts): [Wfi: 16384][Wfe: 16384][src_bf: N*D][dst_bf: N*D]
// Wf* are MFMA B-fragment-linear: chunk (ntile, kstep) holds 64 lanes x 16B
// contiguous; lane (quad<<4|n) element j = W[ntile*16+n][kstep*32+quad*8+j].

__global__ void wfrag_kernel(const float* __restrict__ Wi,
                             const float* __restrict__ We,
                             unsigned short* __restrict__ Wfi,
                             unsigned short* __restrict__ Wfe) {
    int id = blockIdx.x * blockDim.x + threadIdx.x;   // 0..4095
    int mat = id >> 11;
    int idx = id & 2047;          // ntile<<8 | kstep<<6 | lane
    int lane = idx & 63;
    int kstep = (idx >> 6) & 3;
    int ntile = idx >> 8;
    int n = lane & 15, quad = lane >> 4;
    int row = ntile * 16 + n;
    int k0 = kstep * 32 + quad * 8;
    const float* W = mat ? We : Wi;
    unsigned short* Wf = mat ? Wfe : Wfi;
    #pragma unroll
    for (int j = 0; j < 8; ++j)
        Wf[idx * 8 + j] = f2bf(W[row * D + k0 + j]);
}

__global__ void cvt_kernel(const float* __restrict__ x,
                           unsigned short* __restrict__ xb, int n4) {
    int i = blockIdx.x * blockDim.x + threadIdx.x;
    if (i < n4) {
        float4 v = ((const float4*)x)[i];
        ushort4 o;
        o.x = f2bf(v.x); o.y = f2bf(v.y); o.z = f2bf(v.z); o.w = f2bf(v.w);
        ((ushort4*)xb)[i] = o;
    }
}

// self_msg = dst_x @ W_intra^T (pre-activation), MFMA, no LDS.
// Block 256 = 4 independent waves; wave w owns rows r0 + w*16 .. +15.
__global__ __launch_bounds__(256) void node_mfma_kernel(
    const unsigned short* __restrict__ dst_bf,
    const unsigned short* __restrict__ Wfi, float* __restrict__ out) {
    int t = threadIdx.x, lane = t & 63, w = t >> 6;
    int quad = lane >> 4, nl = lane & 15;
    int r0 = blockIdx.x * 64 + w * 16;
    int rc = r0 + nl;
    if (rc > N_NODES - 1) rc = N_NODES - 1;   // clamp tail loads
    const unsigned short* xr = dst_bf + (size_t)rc * D;
    const short8* Wv = (const short8*)Wfi;
    f32x4 acc[8];
    #pragma unroll
    for (int nt = 0; nt < 8; ++nt) acc[nt] = (f32x4){0.f, 0.f, 0.f, 0.f};
    #pragma unroll
    for (int ks = 0; ks < 4; ++ks) {
        short8 a = *(const short8*)(xr + ks * 32 + quad * 8);
        #pragma unroll
        for (int nt = 0; nt < 8; ++nt) {
            short8 b = Wv[(nt * 4 + ks) * 64 + lane];
            acc[nt] = __builtin_amdgcn_mfma_f32_16x16x32_bf16(a, b, acc[nt], 0, 0, 0);
        }
    }
    #pragma unroll
    for (int nt = 0; nt < 8; ++nt)
        #pragma unroll
        for (int r = 0; r < 4; ++r) {
            int row = r0 + quad * 4 + r;      // C/D: col=lane&15, row=quad*4+reg
            if (row < N_NODES)
                out[(size_t)row * D + nt * 16 + nl] = acc[nt][r];
        }
}

// Fused edge GEMM: msg = ew * ([src[s] | src[s]*dst[t]] @ [Wi;We]^T), K=256.
// No intra array. No GEMM LDS. Epilogue: C tile -> padded LDS -> coalesced
// atomicAdd into out[dst].
__global__ __launch_bounds__(256) void edge_mfma_kernel(
    const unsigned short* __restrict__ src_bf,
    const unsigned short* __restrict__ dst_bf,
    const int* __restrict__ src_idx, const int* __restrict__ dst_idx,
    const float* __restrict__ ew,
    const unsigned short* __restrict__ Wfi,
    const unsigned short* __restrict__ Wfe,
    float* __restrict__ out) {
    __shared__ float CT[64 * 132];   // stride 132: 2-way banks on write (free)
    int t = threadIdx.x, lane = t & 63, w = t >> 6;
    int quad = lane >> 4, nl = lane & 15;
    int e0 = blockIdx.x * 64 + w * 16;
    int e_l = e0 + nl;
    int s_l = src_idx[e_l], t_l = dst_idx[e_l];
    const unsigned short* sp = src_bf + (size_t)s_l * D;
    const unsigned short* dp = dst_bf + (size_t)t_l * D;
    const short8* Wiv = (const short8*)Wfi;
    const short8* Wev = (const short8*)Wfe;
    f32x4 acc[8];
    #pragma unroll
    for (int nt = 0; nt < 8; ++nt) acc[nt] = (f32x4){0.f, 0.f, 0.f, 0.f};

    #pragma unroll
    for (int ks = 0; ks < 4; ++ks) {
        ushort8 sv = *(const ushort8*)(sp + ks * 32 + quad * 8);
        ushort8 dv = *(const ushort8*)(dp + ks * 32 + quad * 8);
        short8 a1, a2;
        #pragma unroll
        for (int j = 0; j < 8; ++j) {
            a1[j] = (short)sv[j];
            a2[j] = (short)f2bf(bf2f(sv[j]) * bf2f(dv[j]));
        }
        #pragma unroll
        for (int nt = 0; nt < 8; ++nt)
            acc[nt] = __builtin_amdgcn_mfma_f32_16x16x32_bf16(
                a1, Wiv[(nt * 4 + ks) * 64 + lane], acc[nt], 0, 0, 0);
        #pragma unroll
        for (int nt = 0; nt < 8; ++nt)
            acc[nt] = __builtin_amdgcn_mfma_f32_16x16x32_bf16(
                a2, Wev[(nt * 4 + ks) * 64 + lane], acc[nt], 0, 0, 0);
    }

    // C regs -> LDS (rows are wave-private)
    #pragma unroll
    for (int nt = 0; nt < 8; ++nt)
        #pragma unroll
        for (int r = 0; r < 4; ++r)
            CT[(w * 16 + quad * 4 + r) * 132 + nt * 16 + nl] = acc[nt][r];
    __syncthreads();

    // coalesced atomic scatter, one destination row at a time
    for (int m = 0; m < 16; ++m) {
        int e = e0 + m;
        int tm = dst_idx[e];          // wave-uniform -> scalar load
        float wm = ew[e];
        #pragma unroll
        for (int j = 0; j < 2; ++j) {
            int c = j * 64 + lane;
            atomicAdd(out + (size_t)tm * D + c, wm * CT[(w * 16 + m) * 132 + c]);
        }
    }
}

__global__ void leaky_relu_kernel(float* __restrict__ out, int n) {
    int i = blockIdx.x * blockDim.x + threadIdx.x;
    if (i < n) {
        float v = out[i];
        out[i] = v > 0.0f ? v : 0.01f * v;
    }
}

extern "C" void kernel_launch(void* const* d_in, const int* in_sizes, int n_in,
                              void* d_out, int out_size, void* d_ws, size_t ws_size,
                              hipStream_t stream) {
    const float* src_x = (const float*)d_in[0];
    const float* dst_x = (const float*)d_in[1];
    const int*   eidx  = (const int*)d_in[2];     // [2, E] flat: src then dst
    const float* ew    = (const float*)d_in[3];   // [E, 1]
    const float* Wi    = (const float*)d_in[4];   // [D, D]
    const float* We    = (const float*)d_in[5];   // [D, D]
    float* out = (float*)d_out;

    unsigned short* wsu    = (unsigned short*)d_ws;
    unsigned short* Wfi    = wsu;                       // 16384
    unsigned short* Wfe    = wsu + 16384;               // 16384
    unsigned short* src_bf = wsu + 32768;               // N*D
    unsigned short* dst_bf = src_bf + (size_t)N_NODES * D;

    const int* src_idx = eidx;
    const int* dst_idx = eidx + N_EDGES;

    wfrag_kernel<<<16, 256, 0, stream>>>(Wi, We, Wfi, Wfe);

    int n4 = N_NODES * D / 4;
    cvt_kernel<<<(n4 + 255) / 256, 256, 0, stream>>>(src_x, src_bf, n4);
    cvt_kernel<<<(n4 + 255) / 256, 256, 0, stream>>>(dst_x, dst_bf, n4);

    node_mfma_kernel<<<(N_NODES + 63) / 64, 256, 0, stream>>>(dst_bf, Wfi, out);

    edge_mfma_kernel<<<N_EDGES / 64, 256, 0, stream>>>(src_bf, dst_bf, src_idx,
                                                       dst_idx, ew, Wfi, Wfe, out);

    leaky_relu_kernel<<<(N_NODES * D + 255) / 256, 256, 0, stream>>>(out, N_NODES * D);
}

// Round 5
// 458.679 us; speedup vs baseline: 5.1496x; 1.0912x over previous
//
#include <hip/hip_runtime.h>
#include <hip/hip_bf16.h>

#define N_NODES 100000
#define N_EDGES 600000
#define D 128
#define NG_E 10   // 16-edge groups per block: 600000/(16*10) = 3750 blocks
#define NG_N 10   // 16-row  groups per block: 100000/(16*10) = 625 blocks

typedef __attribute__((ext_vector_type(8))) short short8;
typedef __attribute__((ext_vector_type(8))) unsigned short ushort8;
typedef __attribute__((ext_vector_type(4))) unsigned int uint4v;
typedef __attribute__((ext_vector_type(4))) float f32x4;

union V8 { short8 s8; ushort8 u8; uint4v u4; };

__device__ __forceinline__ unsigned short f2bf(float f) {
    unsigned u = __float_as_uint(f);
    u += 0x7FFF + ((u >> 16) & 1);   // RNE
    return (unsigned short)(u >> 16);
}

// ws layout (ushorts): [Wfi: 16384][Wfe: 16384][src_bf: N*D][dst_bf: N*D]
// Wf* are MFMA B-fragment-linear: chunk (nt, ks) holds 64 lanes x 16B;
// lane (quad<<4|n) element j = W[nt*16+n][ks*32+quad*8+j].

__global__ void wfrag_kernel(const float* __restrict__ Wi,
                             const float* __restrict__ We,
                             unsigned short* __restrict__ Wfi,
                             unsigned short* __restrict__ Wfe) {
    int id = blockIdx.x * blockDim.x + threadIdx.x;   // 0..4095
    int mat = id >> 11;
    int idx = id & 2047;          // nt<<8 | ks<<6 | lane
    int lane = idx & 63;
    int ks = (idx >> 6) & 3;
    int nt = idx >> 8;
    int n = lane & 15, quad = lane >> 4;
    int row = nt * 16 + n;
    int k0 = ks * 32 + quad * 8;
    const float* W = mat ? We : Wi;
    unsigned short* Wf = mat ? Wfe : Wfi;
    #pragma unroll
    for (int j = 0; j < 8; ++j)
        Wf[idx * 8 + j] = f2bf(W[row * D + k0 + j]);
}

__global__ void cvt_kernel(const float* __restrict__ x,
                           unsigned short* __restrict__ xb, int n4) {
    int i = blockIdx.x * blockDim.x + threadIdx.x;
    if (i < n4) {
        float4 v = ((const float4*)x)[i];
        ushort4 o;
        o.x = f2bf(v.x); o.y = f2bf(v.y); o.z = f2bf(v.z); o.w = f2bf(v.w);
        ((ushort4*)xb)[i] = o;
    }
}

// self_msg = dst_x @ W_intra^T. Wave w owns cols [w*32, w*32+32); its 8
// B-frags live in registers for the whole block (NG_N row-groups).
__global__ __launch_bounds__(256, 4) void node_mfma2_kernel(
    const unsigned short* __restrict__ dst_bf,
    const unsigned short* __restrict__ Wfi, float* __restrict__ out) {
    int t = threadIdx.x, lane = t & 63, w = t >> 6;
    int quad = lane >> 4, nl = lane & 15;
    const short8* Wv = (const short8*)Wfi;
    short8 Bf[2][4];
    #pragma unroll
    for (int ntl = 0; ntl < 2; ++ntl)
        #pragma unroll
        for (int ks = 0; ks < 4; ++ks)
            Bf[ntl][ks] = Wv[((2 * w + ntl) * 4 + ks) * 64 + lane];

    int base = blockIdx.x * (NG_N * 16);
    for (int g = 0; g < NG_N; ++g) {
        int gbase = base + g * 16;
        const unsigned short* xr = dst_bf + (size_t)(gbase + nl) * D + quad * 8;
        f32x4 acc[2];
        acc[0] = (f32x4){0.f, 0.f, 0.f, 0.f};
        acc[1] = (f32x4){0.f, 0.f, 0.f, 0.f};
        #pragma unroll
        for (int ks = 0; ks < 4; ++ks) {
            short8 a = *(const short8*)(xr + ks * 32);
            acc[0] = __builtin_amdgcn_mfma_f32_16x16x32_bf16(a, Bf[0][ks], acc[0], 0, 0, 0);
            acc[1] = __builtin_amdgcn_mfma_f32_16x16x32_bf16(a, Bf[1][ks], acc[1], 0, 0, 0);
        }
        #pragma unroll
        for (int ntl = 0; ntl < 2; ++ntl)
            #pragma unroll
            for (int r = 0; r < 4; ++r)
                out[(size_t)(gbase + quad * 4 + r) * D + (2 * w + ntl) * 16 + nl]
                    = acc[ntl][r];
    }
}

// Fused edge GEMM: msg = ew * (src[s]@Wi^T + (src[s]*dst[t])@We^T).
// Wave w owns cols [w*32, w*32+32): 16 resident B-frags (64 VGPRs), reused
// across NG_E groups. Epilogue: direct atomicAdd from acc regs — each
// instruction covers 4 dst rows x 16 consecutive floats = 4 full 64B lines.
__global__ __launch_bounds__(256, 4) void edge_mfma2_kernel(
    const unsigned short* __restrict__ src_bf,
    const unsigned short* __restrict__ dst_bf,
    const int* __restrict__ src_idx, const int* __restrict__ dst_idx,
    const float* __restrict__ ew,
    const unsigned short* __restrict__ Wfi,
    const unsigned short* __restrict__ Wfe,
    float* __restrict__ out) {
    int t = threadIdx.x, lane = t & 63, w = t >> 6;
    int quad = lane >> 4, nl = lane & 15;
    const short8* Wiv = (const short8*)Wfi;
    const short8* Wev = (const short8*)Wfe;
    short8 Bi[2][4], Be[2][4];
    #pragma unroll
    for (int ntl = 0; ntl < 2; ++ntl)
        #pragma unroll
        for (int ks = 0; ks < 4; ++ks) {
            Bi[ntl][ks] = Wiv[((2 * w + ntl) * 4 + ks) * 64 + lane];
            Be[ntl][ks] = Wev[((2 * w + ntl) * 4 + ks) * 64 + lane];
        }

    int base = blockIdx.x * (NG_E * 16);
    for (int g = 0; g < NG_E; ++g) {
        int gbase = base + g * 16;
        int s_l = src_idx[gbase + nl];
        int t_l = dst_idx[gbase + nl];
        const unsigned short* sp = src_bf + (size_t)s_l * D + quad * 8;
        const unsigned short* dp = dst_bf + (size_t)t_l * D + quad * 8;
        f32x4 acc[2];
        acc[0] = (f32x4){0.f, 0.f, 0.f, 0.f};
        acc[1] = (f32x4){0.f, 0.f, 0.f, 0.f};
        #pragma unroll
        for (int ks = 0; ks < 4; ++ks) {
            V8 sU, dU, pU;
            sU.u8 = *(const ushort8*)(sp + ks * 32);
            dU.u8 = *(const ushort8*)(dp + ks * 32);
            #pragma unroll
            for (int h = 0; h < 4; ++h) {
                unsigned su = sU.u4[h], du = dU.u4[h];
                float p0 = __uint_as_float(su << 16) * __uint_as_float(du << 16);
                float p1 = __uint_as_float(su & 0xFFFF0000u) *
                           __uint_as_float(du & 0xFFFF0000u);
                __hip_bfloat162 h2 = __float22bfloat162_rn(make_float2(p0, p1));
                pU.u4[h] = *(unsigned*)&h2;
            }
            short8 a1 = sU.s8, a2 = pU.s8;
            acc[0] = __builtin_amdgcn_mfma_f32_16x16x32_bf16(a1, Bi[0][ks], acc[0], 0, 0, 0);
            acc[1] = __builtin_amdgcn_mfma_f32_16x16x32_bf16(a1, Bi[1][ks], acc[1], 0, 0, 0);
            acc[0] = __builtin_amdgcn_mfma_f32_16x16x32_bf16(a2, Be[0][ks], acc[0], 0, 0, 0);
            acc[1] = __builtin_amdgcn_mfma_f32_16x16x32_bf16(a2, Be[1][ks], acc[1], 0, 0, 0);
        }
        #pragma unroll
        for (int r = 0; r < 4; ++r) {
            int e = gbase + quad * 4 + r;
            int dr = dst_idx[e];          // 4 distinct addrs/wave -> L1 broadcast
            float wm = ew[e];
            float* orow = out + (size_t)dr * D;
            atomicAdd(orow + (2 * w) * 16 + nl, wm * acc[0][r]);
            atomicAdd(orow + (2 * w + 1) * 16 + nl, wm * acc[1][r]);
        }
    }
}

__global__ void leaky_relu4_kernel(float* __restrict__ out, int n4) {
    int i = blockIdx.x * blockDim.x + threadIdx.x;
    if (i < n4) {
        float4 v = ((const float4*)out)[i];
        v.x = v.x > 0.f ? v.x : 0.01f * v.x;
        v.y = v.y > 0.f ? v.y : 0.01f * v.y;
        v.z = v.z > 0.f ? v.z : 0.01f * v.z;
        v.w = v.w > 0.f ? v.w : 0.01f * v.w;
        ((float4*)out)[i] = v;
    }
}

extern "C" void kernel_launch(void* const* d_in, const int* in_sizes, int n_in,
                              void* d_out, int out_size, void* d_ws, size_t ws_size,
                              hipStream_t stream) {
    const float* src_x = (const float*)d_in[0];
    const float* dst_x = (const float*)d_in[1];
    const int*   eidx  = (const int*)d_in[2];     // [2, E] flat: src then dst
    const float* ew    = (const float*)d_in[3];   // [E, 1]
    const float* Wi    = (const float*)d_in[4];   // [D, D]
    const float* We    = (const float*)d_in[5];   // [D, D]
    float* out = (float*)d_out;

    unsigned short* wsu    = (unsigned short*)d_ws;
    unsigned short* Wfi    = wsu;                       // 16384
    unsigned short* Wfe    = wsu + 16384;               // 16384
    unsigned short* src_bf = wsu + 32768;               // N*D
    unsigned short* dst_bf = src_bf + (size_t)N_NODES * D;

    const int* src_idx = eidx;
    const int* dst_idx = eidx + N_EDGES;

    wfrag_kernel<<<16, 256, 0, stream>>>(Wi, We, Wfi, Wfe);

    int n4 = N_NODES * D / 4;
    cvt_kernel<<<(n4 + 255) / 256, 256, 0, stream>>>(src_x, src_bf, n4);
    cvt_kernel<<<(n4 + 255) / 256, 256, 0, stream>>>(dst_x, dst_bf, n4);

    node_mfma2_kernel<<<N_NODES / (16 * NG_N), 256, 0, stream>>>(dst_bf, Wfi, out);

    edge_mfma2_kernel<<<N_EDGES / (16 * NG_E), 256, 0, stream>>>(
        src_bf, dst_bf, src_idx, dst_idx, ew, Wfi, Wfe, out);

    leaky_relu4_kernel<<<(n4 + 255) / 256, 256, 0, stream>>>(out, n4);
}

// Round 6
// 436.624 us; speedup vs baseline: 5.4097x; 1.0505x over previous
//
#include <hip/hip_runtime.h>
#include <hip/hip_bf16.h>

#define N_NODES 100000
#define N_EDGES 600000
#define D 128
#define NG_E 12   // 16-edge groups per block: 600000/(16*12) = 3125 blocks
#define NG_N 10   // 16-row  groups per block: 100000/(16*10) = 625 blocks

typedef __attribute__((ext_vector_type(8))) short short8;
typedef __attribute__((ext_vector_type(8))) unsigned short ushort8;
typedef __attribute__((ext_vector_type(4))) unsigned int uint4v;
typedef __attribute__((ext_vector_type(4))) float f32x4;

union V8 { short8 s8; ushort8 u8; uint4v u4; };

__device__ __forceinline__ unsigned short f2bf(float f) {
    unsigned u = __float_as_uint(f);
    u += 0x7FFF + ((u >> 16) & 1);   // RNE
    return (unsigned short)(u >> 16);
}

// ws layout (ushorts): [Wfi: 16384][Wfe: 16384][src_bf: N*D][dst_bf: N*D]
// Wf* are MFMA B-fragment-linear: chunk (nt, ks) holds 64 lanes x 16B;
// lane (quad<<4|n) element j = W[nt*16+n][ks*32+quad*8+j].

__global__ void wfrag_kernel(const float* __restrict__ Wi,
                             const float* __restrict__ We,
                             unsigned short* __restrict__ Wfi,
                             unsigned short* __restrict__ Wfe) {
    int id = blockIdx.x * blockDim.x + threadIdx.x;   // 0..4095
    int mat = id >> 11;
    int idx = id & 2047;          // nt<<8 | ks<<6 | lane
    int lane = idx & 63;
    int ks = (idx >> 6) & 3;
    int nt = idx >> 8;
    int n = lane & 15, quad = lane >> 4;
    int row = nt * 16 + n;
    int k0 = ks * 32 + quad * 8;
    const float* W = mat ? We : Wi;
    unsigned short* Wf = mat ? Wfe : Wfi;
    #pragma unroll
    for (int j = 0; j < 8; ++j)
        Wf[idx * 8 + j] = f2bf(W[row * D + k0 + j]);
}

// Converts both node arrays in one launch.
__global__ void cvt2_kernel(const float* __restrict__ a,
                            const float* __restrict__ b,
                            unsigned short* __restrict__ ab,
                            unsigned short* __restrict__ bb, int n4) {
    int i = blockIdx.x * blockDim.x + threadIdx.x;
    const float4* src;
    ushort4* dst;
    int j;
    if (i < n4) {
        j = i; src = (const float4*)a; dst = (ushort4*)ab;
    } else if (i < 2 * n4) {
        j = i - n4; src = (const float4*)b; dst = (ushort4*)bb;
    } else return;
    float4 v = src[j];
    ushort4 o;
    o.x = f2bf(v.x); o.y = f2bf(v.y); o.z = f2bf(v.z); o.w = f2bf(v.w);
    dst[j] = o;
}

// self_msg = dst_x @ W_intra^T. Wave w owns cols [w*32, w*32+32); its 8
// B-frags live in registers for the whole block (NG_N row-groups).
__global__ __launch_bounds__(256, 4) void node_mfma2_kernel(
    const unsigned short* __restrict__ dst_bf,
    const unsigned short* __restrict__ Wfi, float* __restrict__ out) {
    int t = threadIdx.x, lane = t & 63, w = t >> 6;
    int quad = lane >> 4, nl = lane & 15;
    const short8* Wv = (const short8*)Wfi;
    short8 Bf[2][4];
    #pragma unroll
    for (int ntl = 0; ntl < 2; ++ntl)
        #pragma unroll
        for (int ks = 0; ks < 4; ++ks)
            Bf[ntl][ks] = Wv[((2 * w + ntl) * 4 + ks) * 64 + lane];

    int base = blockIdx.x * (NG_N * 16);
    for (int g = 0; g < NG_N; ++g) {
        int gbase = base + g * 16;
        const unsigned short* xr = dst_bf + (size_t)(gbase + nl) * D + quad * 8;
        f32x4 acc[2];
        acc[0] = (f32x4){0.f, 0.f, 0.f, 0.f};
        acc[1] = (f32x4){0.f, 0.f, 0.f, 0.f};
        #pragma unroll
        for (int ks = 0; ks < 4; ++ks) {
            short8 a = *(const short8*)(xr + ks * 32);
            acc[0] = __builtin_amdgcn_mfma_f32_16x16x32_bf16(a, Bf[0][ks], acc[0], 0, 0, 0);
            acc[1] = __builtin_amdgcn_mfma_f32_16x16x32_bf16(a, Bf[1][ks], acc[1], 0, 0, 0);
        }
        #pragma unroll
        for (int ntl = 0; ntl < 2; ++ntl)
            #pragma unroll
            for (int r = 0; r < 4; ++r)
                out[(size_t)(gbase + quad * 4 + r) * D + (2 * w + ntl) * 16 + nl]
                    = acc[ntl][r];
    }
}

// Fused edge GEMM: msg = ew * (src[s]@Wi^T + (src[s]*dst[t])@We^T).
// Wave w owns cols [w*32, w*32+32): 16 resident B-frags.
// Idx/ew loaded one coalesced 64-edge chunk at a time, distributed via __shfl.
// A-gathers software-pipelined one group ahead (double-buffered registers).
__global__ __launch_bounds__(256, 2) void edge_mfma3_kernel(
    const unsigned short* __restrict__ src_bf,
    const unsigned short* __restrict__ dst_bf,
    const int* __restrict__ src_idx, const int* __restrict__ dst_idx,
    const float* __restrict__ ew,
    const unsigned short* __restrict__ Wfi,
    const unsigned short* __restrict__ Wfe,
    float* __restrict__ out) {
    int t = threadIdx.x, lane = t & 63, w = t >> 6;
    int quad = lane >> 4, nl = lane & 15;
    const short8* Wiv = (const short8*)Wfi;
    const short8* Wev = (const short8*)Wfe;
    short8 Bi[2][4], Be[2][4];
    #pragma unroll
    for (int ntl = 0; ntl < 2; ++ntl)
        #pragma unroll
        for (int ks = 0; ks < 4; ++ks) {
            Bi[ntl][ks] = Wiv[((2 * w + ntl) * 4 + ks) * 64 + lane];
            Be[ntl][ks] = Wev[((2 * w + ntl) * 4 + ks) * 64 + lane];
        }

    int base = blockIdx.x * (NG_E * 16);

    // chunk 0 (groups 0..3): 64 consecutive edges' idx/weight, one per lane
    int sC = src_idx[base + lane];
    int dC = dst_idx[base + lane];
    float eC = ew[base + lane];

    V8 sv[2][4], dv[2][4];   // double-buffered A-gathers

    // prefetch group 0
    {
        int sl = __shfl(sC, nl);
        int tl = __shfl(dC, nl);
        const unsigned short* sp = src_bf + (size_t)sl * D + quad * 8;
        const unsigned short* dp = dst_bf + (size_t)tl * D + quad * 8;
        #pragma unroll
        for (int ks = 0; ks < 4; ++ks) {
            sv[0][ks].u8 = *(const ushort8*)(sp + ks * 32);
            dv[0][ks].u8 = *(const ushort8*)(dp + ks * 32);
        }
    }

    #pragma unroll
    for (int g = 0; g < NG_E; ++g) {
        const int buf = g & 1, nbuf = buf ^ 1;
        int sN = sC, dN = dC;
        float eN = eC;
        bool roll = false;

        // --- issue next group's gathers before touching current buffers
        if (g + 1 < NG_E) {
            const int gn = g + 1;
            if ((gn & 3) == 0) {          // new 64-edge chunk
                int cb = base + gn * 16;
                sN = src_idx[cb + lane];
                dN = dst_idx[cb + lane];
                eN = ew[cb + lane];
                roll = true;
            }
            const int gi = gn & 3;
            int sl = __shfl(roll ? sN : sC, gi * 16 + nl);
            int tl = __shfl(roll ? dN : dC, gi * 16 + nl);
            const unsigned short* sp = src_bf + (size_t)sl * D + quad * 8;
            const unsigned short* dp = dst_bf + (size_t)tl * D + quad * 8;
            #pragma unroll
            for (int ks = 0; ks < 4; ++ks) {
                sv[nbuf][ks].u8 = *(const ushort8*)(sp + ks * 32);
                dv[nbuf][ks].u8 = *(const ushort8*)(dp + ks * 32);
            }
        }

        // --- compute current group
        f32x4 acc[2];
        acc[0] = (f32x4){0.f, 0.f, 0.f, 0.f};
        acc[1] = (f32x4){0.f, 0.f, 0.f, 0.f};
        #pragma unroll
        for (int ks = 0; ks < 4; ++ks) {
            V8 pU;
            #pragma unroll
            for (int h = 0; h < 4; ++h) {
                unsigned su = sv[buf][ks].u4[h], du = dv[buf][ks].u4[h];
                float p0 = __uint_as_float(su << 16) * __uint_as_float(du << 16);
                float p1 = __uint_as_float(su & 0xFFFF0000u) *
                           __uint_as_float(du & 0xFFFF0000u);
                __hip_bfloat162 h2 = __float22bfloat162_rn(make_float2(p0, p1));
                pU.u4[h] = *(unsigned*)&h2;
            }
            short8 a1 = sv[buf][ks].s8, a2 = pU.s8;
            acc[0] = __builtin_amdgcn_mfma_f32_16x16x32_bf16(a1, Bi[0][ks], acc[0], 0, 0, 0);
            acc[1] = __builtin_amdgcn_mfma_f32_16x16x32_bf16(a1, Bi[1][ks], acc[1], 0, 0, 0);
            acc[0] = __builtin_amdgcn_mfma_f32_16x16x32_bf16(a2, Be[0][ks], acc[0], 0, 0, 0);
            acc[1] = __builtin_amdgcn_mfma_f32_16x16x32_bf16(a2, Be[1][ks], acc[1], 0, 0, 0);
        }

        // --- epilogue: dst/weight via shuffle; 64B-line-covering atomics
        const int gi = g & 3;
        #pragma unroll
        for (int r = 0; r < 4; ++r) {
            int srcl = gi * 16 + quad * 4 + r;
            int dr = __shfl(dC, srcl);
            float wm = __shfl(eC, srcl);
            float* orow = out + (size_t)dr * D;
            atomicAdd(orow + (2 * w) * 16 + nl, wm * acc[0][r]);
            atomicAdd(orow + (2 * w + 1) * 16 + nl, wm * acc[1][r]);
        }

        if (roll) { sC = sN; dC = dN; eC = eN; }
    }
}

__global__ void leaky_relu4_kernel(float* __restrict__ out, int n4) {
    int i = blockIdx.x * blockDim.x + threadIdx.x;
    if (i < n4) {
        float4 v = ((const float4*)out)[i];
        v.x = v.x > 0.f ? v.x : 0.01f * v.x;
        v.y = v.y > 0.f ? v.y : 0.01f * v.y;
        v.z = v.z > 0.f ? v.z : 0.01f * v.z;
        v.w = v.w > 0.f ? v.w : 0.01f * v.w;
        ((float4*)out)[i] = v;
    }
}

extern "C" void kernel_launch(void* const* d_in, const int* in_sizes, int n_in,
                              void* d_out, int out_size, void* d_ws, size_t ws_size,
                              hipStream_t stream) {
    const float* src_x = (const float*)d_in[0];
    const float* dst_x = (const float*)d_in[1];
    const int*   eidx  = (const int*)d_in[2];     // [2, E] flat: src then dst
    const float* ew    = (const float*)d_in[3];   // [E, 1]
    const float* Wi    = (const float*)d_in[4];   // [D, D]
    const float* We    = (const float*)d_in[5];   // [D, D]
    float* out = (float*)d_out;

    unsigned short* wsu    = (unsigned short*)d_ws;
    unsigned short* Wfi    = wsu;                       // 16384
    unsigned short* Wfe    = wsu + 16384;               // 16384
    unsigned short* src_bf = wsu + 32768;               // N*D
    unsigned short* dst_bf = src_bf + (size_t)N_NODES * D;

    const int* src_idx = eidx;
    const int* dst_idx = eidx + N_EDGES;

    wfrag_kernel<<<16, 256, 0, stream>>>(Wi, We, Wfi, Wfe);

    int n4 = N_NODES * D / 4;
    cvt2_kernel<<<(2 * n4 + 255) / 256, 256, 0, stream>>>(src_x, dst_x,
                                                          src_bf, dst_bf, n4);

    node_mfma2_kernel<<<N_NODES / (16 * NG_N), 256, 0, stream>>>(dst_bf, Wfi, out);

    edge_mfma3_kernel<<<N_EDGES / (16 * NG_E), 256, 0, stream>>>(
        src_bf, dst_bf, src_idx, dst_idx, ew, Wfi, Wfe, out);

    leaky_relu4_kernel<<<(n4 + 255) / 256, 256, 0, stream>>>(out, n4);
}